// Round 12
// baseline (292.851 us; speedup 1.0000x reference)
//
#include <hip/hip_runtime.h>
#include <stdint.h>
#include <stddef.h>

// ---------------- problem constants ----------------
constexpr int kH = 496, kW = 432;
constexpr int HWSZ = kH * kW;          // 214272
constexpr int NANCH = HWSZ * 6;        // 1285632 anchors
constexpr int NPRE = 4096;             // nms_pre
constexpr int MAXNUM = 500;
constexpr int CAND_CAP = 8192;
constexpr float SCORE_THR_F = 0.1f;
constexpr float PIF  = 3.14159265358979323846f;  // rounds to f32 pi
constexpr float HPIF = 1.57079632679489661923f;  // rounds to f32 pi/2

// histogram: bin = float_bits >> 15; sigmoids < 2.0 -> bin < 32768.
constexpr int NBINS  = 32768;
constexpr int NPAIR  = NBINS / 2;      // packed u16 pairs in LDS = 64 KB
constexpr int NB_H   = 256;            // histogram blocks

// pad key: sorts AFTER every real key (real high32 = ~bits <= 0xFFFFFFFE).
constexpr uint64_t PADKEY = 0xFFFFFFFF00000000ull;

// ---------------- workspace layout (bytes) ----------------
constexpr size_t HIST_OFF  = 0;                                   // u32[32768] = 128 KB
constexpr size_t MISC_OFF  = 131072;                              // u32[64]: 0=cand_cnt 8..10=Vc_out 12..14=Vthr
constexpr size_t ZERO_BYTES= 131072 + 256;                        // hist + misc, one memset
constexpr size_t MS_OFF    = 131328;                              // f32[NANCH]
constexpr size_t CAND_OFF  = MS_OFF + 4ull * NANCH;               // u64[8192]
constexpr size_t SEL_OFF   = CAND_OFF + 8ull * CAND_CAP;          // u32[NPRE]
constexpr size_t SC3_OFF   = SEL_OFF + 4ull * NPRE;               // f32[NPRE*3]
constexpr size_t DSC_OFF   = SC3_OFF + 4ull * NPRE * 3;           // u32[NPRE]
constexpr size_t BB7_OFF   = DSC_OFF + 4ull * NPRE;               // f32[NPRE*7]
constexpr size_t BOX4_OFF  = BB7_OFF + 4ull * NPRE * 7;           // f32[NPRE*4]
constexpr size_t AREA_OFF  = BOX4_OFF + 4ull * NPRE * 4;          // f32[NPRE]
constexpr size_t ORD_OFF   = AREA_OFF + 4ull * NPRE;              // u32[3*NPRE]
constexpr size_t PMASK_OFF = ORD_OFF + 4ull * 3 * NPRE;           // u64[3*NPRE*64]  (6 MB)
constexpr size_t KEEPW_OFF = PMASK_OFF + 8ull * 3 * NPRE * 64;    // u64[3*64]
constexpr size_t OUTK_OFF  = KEEPW_OFF + 8ull * 3 * 64;           // u64[2048]

// ---------------- helpers ----------------
__device__ __forceinline__ float sigmoidf_(float x) { return 1.0f / (1.0f + expf(-x)); }

__device__ __forceinline__ uint64_t readlane64(uint64_t v, int lane) {
  uint32_t lo = (uint32_t)__builtin_amdgcn_readlane((int)(uint32_t)(v & 0xffffffffull), lane);
  uint32_t hi = (uint32_t)__builtin_amdgcn_readlane((int)(uint32_t)(v >> 32), lane);
  return (((uint64_t)hi) << 32) | (uint64_t)lo;
}

// ---------------- kernels ----------------

// 1) per-anchor max-of-3-sigmoids + per-block LDS histogram, flushed with
//    scattered device atomics on nonzero bins only.
__global__ __launch_bounds__(256) void k_score(const float* __restrict__ cls,
                                               float* __restrict__ ms,
                                               uint32_t* __restrict__ hist) {
  __shared__ uint32_t h[NPAIR];  // 64 KB, packed u16 pairs
  const int t = threadIdx.x, blk = blockIdx.x;
  for (int i = t; i < NPAIR; i += 256) h[i] = 0;
  __syncthreads();
  for (int p = blk * 256 + t; p < HWSZ; p += NB_H * 256) {
#pragma unroll
    for (int k = 0; k < 6; ++k) {
      float s0 = sigmoidf_(cls[(k * 3 + 0) * HWSZ + p]);
      float s1 = sigmoidf_(cls[(k * 3 + 1) * HWSZ + p]);
      float s2 = sigmoidf_(cls[(k * 3 + 2) * HWSZ + p]);
      float m = fmaxf(s0, fmaxf(s1, s2));
      ms[p * 6 + k] = m;
      uint32_t bin = __float_as_uint(m) >> 15;  // < 32768 (scores < 2.0)
      atomicAdd(&h[bin >> 1], 1u << ((bin & 1) * 16));  // LDS atomic only
    }
  }
  __syncthreads();
  for (int i = t; i < NPAIR; i += 256) {
    uint32_t v = h[i];
    if (v) {
      uint32_t lo = v & 0xFFFFu, hi = v >> 16;
      if (lo) atomicAdd(&hist[2 * i],     lo);  // scattered device atomics
      if (hi) atomicAdd(&hist[2 * i + 1], hi);
    }
  }
}

// 2) compaction with FUSED threshold scan: every block redundantly computes
//    the threshold bin B from the (L2-hot) histogram, then block-aggregates
//    candidates in LDS with ONE global atomic per block. B is deterministic
//    and identical across blocks; replaces the k_scanhist dispatch.
__global__ __launch_bounds__(256) void k_compact(const uint32_t* __restrict__ hist,
                                                 const float* __restrict__ ms,
                                                 uint32_t* __restrict__ misc,
                                                 uint64_t* __restrict__ cand) {
  constexpr int APB = 4096;
  __shared__ uint64_t lbuf[APB];       // 32 KB
  __shared__ uint32_t part[256];
  __shared__ uint32_t suf[257];
  __shared__ uint32_t sB, lcnt, lbase;
  const int t = threadIdx.x;
  // --- preamble: find B s.t. count(bin > B) < 4096 <= count(bin >= B) ---
  const int hb = t * 128;
  uint32_t s = 0;
  const uint4* h4 = (const uint4*)(hist + hb);
#pragma unroll
  for (int q = 0; q < 32; ++q) { uint4 v = h4[q]; s += v.x + v.y + v.z + v.w; }
  part[t] = s;
  if (t == 0) { sB = 0; lcnt = 0; }
  __syncthreads();
  if (t == 0) {
    uint32_t acc = 0;
    suf[256] = 0;
    for (int q = 255; q >= 0; --q) { suf[q] = acc + part[q]; acc = suf[q]; }
  }
  __syncthreads();
  uint32_t above = suf[t + 1];
  if (above < (uint32_t)NPRE && above + part[t] >= (uint32_t)NPRE) {
    uint32_t acc = above;
    for (int b = hb + 127; b >= hb; --b) {
      uint32_t h = hist[b];
      if (acc + h >= (uint32_t)NPRE) { sB = (uint32_t)b; break; }
      acc += h;
    }
  }
  __syncthreads();
  const uint32_t B = sB;
  // --- candidate extraction (block-aggregated) ---
  const int base = blockIdx.x * APB;
#pragma unroll
  for (int q = 0; q < 16; ++q) {
    int a = base + q * 256 + t;        // coalesced
    if (a < NANCH) {
      uint32_t bits = __float_as_uint(ms[a]);
      if ((bits >> 15) >= B) {
        uint32_t sl = atomicAdd(&lcnt, 1u);  // LDS atomic, ~15/block
        lbuf[sl] = (((uint64_t)(~bits)) << 32) | (uint32_t)a;
      }
    }
  }
  __syncthreads();
  const uint32_t n = lcnt;
  if (t == 0 && n > 0) lbase = atomicAdd(&misc[0], n);  // one RMW per block
  __syncthreads();
  if (n > 0) {
    const uint32_t b0 = lbase;
    for (uint32_t i = t; i < n; i += 256) {
      uint32_t slot = b0 + i;
      if (slot < (uint32_t)CAND_CAP) cand[slot] = lbuf[i];
    }
  }
}

// 3) EXACT rank-by-count (order-independent over cand[]; keys unique).
__global__ __launch_bounds__(256) void k_rank(const uint64_t* __restrict__ cand,
                                              const uint32_t* __restrict__ misc,
                                              uint32_t* __restrict__ sel) {
  const int tid = threadIdx.x, ln = tid & 63;
  const int wave = blockIdx.x * 4 + (tid >> 6);   // 0..511
  const int base = wave * 16;
  uint32_t cnt = misc[0];
  if (cnt > (uint32_t)CAND_CAP) cnt = CAND_CAP;
  uint64_t kr[16];
#pragma unroll
  for (int r = 0; r < 16; ++r) kr[r] = cand[base + r];
  uint32_t rnk[16];
#pragma unroll
  for (int r = 0; r < 16; ++r) rnk[r] = 0;
  const int nch = ((int)cnt + 63) >> 6;
  for (int ch = 0; ch < nch; ++ch) {
    uint64_t ck = cand[ch * 64 + ln];
    uint64_t vm = __ballot(ch * 64 + ln < (int)cnt);
#pragma unroll
    for (int r = 0; r < 16; ++r)
      rnk[r] += (uint32_t)__popcll(__ballot(ck < kr[r]) & vm);
  }
#pragma unroll
  for (int r = 0; r < 16; ++r) {
    int row = base + r;
    if (ln == 0 && row < (int)cnt && rnk[r] < (uint32_t)NPRE)
      sel[rnk[r]] = (uint32_t)kr[r];
  }
}

// 4) gather per-anchor data + decode boxes. Also counts V_thr[c] =
//    #{i: sc3[i,c] > 0.1} (block-aggregated) — in score-sorted order the
//    valid bitset is always a PREFIX of this length (predicate monotone),
//    which replaces the old k_vwords kernel exactly.
__global__ __launch_bounds__(256) void k_gather(const uint32_t* __restrict__ sel,
                                                const float* __restrict__ cls,
                                                const float* __restrict__ bbp,
                                                const float* __restrict__ dirp,
                                                const float* __restrict__ priors,
                                                float* __restrict__ sc3,
                                                uint32_t* __restrict__ dsc,
                                                float* __restrict__ bb7,
                                                float* __restrict__ box4,
                                                float* __restrict__ areaA,
                                                uint32_t* __restrict__ misc) {
  __shared__ uint32_t vcnt[3];
  const int t = threadIdx.x, ln = t & 63;
  const int i = blockIdx.x * 256 + t;  // grid exactly covers NPRE
  if (t < 3) vcnt[t] = 0;
  __syncthreads();
  uint32_t a = sel[i];
  uint32_t p = a / 6u;
  uint32_t k = a - p * 6u;
  float sc[3];
#pragma unroll
  for (int c = 0; c < 3; ++c) {
    sc[c] = sigmoidf_(cls[(k * 3 + c) * HWSZ + p]);
    sc3[i * 3 + c] = sc[c];
  }
#pragma unroll
  for (int c = 0; c < 3; ++c) {
    uint64_t m = __ballot(sc[c] > SCORE_THR_F);
    if (ln == 0) atomicAdd(&vcnt[c], (uint32_t)__popcll(m));
  }
  float d0 = dirp[(k * 2 + 0) * HWSZ + p];
  float d1 = dirp[(k * 2 + 1) * HWSZ + p];
  dsc[i] = (d1 > d0) ? 1u : 0u;
  float dt[7], pr[7];
#pragma unroll
  for (int q = 0; q < 7; ++q) dt[q] = bbp[(k * 7 + q) * HWSZ + p];
#pragma unroll
  for (int q = 0; q < 7; ++q) pr[q] = priors[(size_t)a * 7 + q];
  float za = pr[2] + pr[5] * 0.5f;
  float diag = sqrtf(pr[4] * pr[4] + pr[3] * pr[3]);
  float xg = dt[0] * diag + pr[0];
  float yg = dt[1] * diag + pr[1];
  float zg = dt[2] * pr[5] + za;
  float wg = expf(dt[3]) * pr[3];
  float lg = expf(dt[4]) * pr[4];
  float hg = expf(dt[5]) * pr[5];
  float rg = dt[6] + pr[6];
  zg = zg - hg * 0.5f;
  bb7[i * 7 + 0] = xg; bb7[i * 7 + 1] = yg; bb7[i * 7 + 2] = zg;
  bb7[i * 7 + 3] = wg; bb7[i * 7 + 4] = lg; bb7[i * 7 + 5] = hg; bb7[i * 7 + 6] = rg;
  float x1 = xg - wg * 0.5f, y1 = yg - lg * 0.5f;
  float x2 = xg + wg * 0.5f, y2 = yg + lg * 0.5f;
  box4[i * 4 + 0] = x1; box4[i * 4 + 1] = y1; box4[i * 4 + 2] = x2; box4[i * 4 + 3] = y2;
  areaA[i] = (x2 - x1 + 1.0f) * (y2 - y1 + 1.0f);
  __syncthreads();
  if (t < 3) atomicAdd(&misc[12 + t], vcnt[t]);
}

// 5) per-class EXACT rank-by-count on key (~score_bits<<32 | pos).
__global__ __launch_bounds__(256) void k_rankcls(const float* __restrict__ sc3,
                                                 uint32_t* __restrict__ ord) {
  const int tid = threadIdx.x, ln = tid & 63;
  const int c = blockIdx.y;
  const int wave = blockIdx.x * 4 + (tid >> 6);  // 0..255
  const int base = wave * 16;
  uint64_t kr[16];
#pragma unroll
  for (int r = 0; r < 16; ++r) {
    int j = base + r;
    kr[r] = (((uint64_t)(~__float_as_uint(sc3[j * 3 + c]))) << 32) | (uint32_t)j;
  }
  uint32_t rnk[16];
#pragma unroll
  for (int r = 0; r < 16; ++r) rnk[r] = 0;
  for (int ch = 0; ch < NPRE / 64; ++ch) {
    int j = ch * 64 + ln;
    uint64_t ck = (((uint64_t)(~__float_as_uint(sc3[j * 3 + c]))) << 32) | (uint32_t)j;
#pragma unroll
    for (int r = 0; r < 16; ++r)
      rnk[r] += (uint32_t)__popcll(__ballot(ck < kr[r]));
  }
#pragma unroll
  for (int r = 0; r < 16; ++r)
    if (ln == 0) ord[c * NPRE + rnk[r]] = (uint32_t)(base + r);
}

// 6) suppression bitmask in per-class sorted order; UPPER TRIANGLE ONLY.
__global__ void k_mask(const uint32_t* __restrict__ ord, const float* __restrict__ box4,
                       const float* __restrict__ areaA, uint64_t* __restrict__ pmask) {
  int c = blockIdx.z, it = blockIdx.y, jt = blockIdx.x, t = threadIdx.x;
  if (jt < it) return;
  __shared__ float jx1[64], jy1[64], jx2[64], jy2[64], jar[64];
  int j = ord[c * NPRE + jt * 64 + t];
  jx1[t] = box4[j * 4 + 0]; jy1[t] = box4[j * 4 + 1];
  jx2[t] = box4[j * 4 + 2]; jy2[t] = box4[j * 4 + 3];
  jar[t] = areaA[j];
  __syncthreads();
  int I = it * 64 + t;
  int i = ord[c * NPRE + I];
  float x1 = box4[i * 4 + 0], y1 = box4[i * 4 + 1];
  float x2 = box4[i * 4 + 2], y2 = box4[i * 4 + 3];
  float ar = areaA[i];
  uint64_t bits = 0;
  for (int b = 0; b < 64; ++b) {
    float xx1 = fmaxf(x1, jx1[b]), yy1 = fmaxf(y1, jy1[b]);
    float xx2 = fminf(x2, jx2[b]), yy2 = fminf(y2, jy2[b]);
    float iw = fmaxf(0.0f, xx2 - xx1 + 1.0f);
    float ih = fmaxf(0.0f, yy2 - yy1 + 1.0f);
    float inter = iw * ih;
    float iou = inter / (ar + jar[b] - inter);
    bits |= ((uint64_t)(iou > 0.5f)) << b;
  }
  pmask[((size_t)(c * NPRE + I)) * 64 + (size_t)jt] = bits;
}

// 7) tiled serial greedy NMS cascade with EARLY EXIT at 500 keeps.
//    avail initialized from the prefix-validity count Vth = misc[12+c].
__global__ __launch_bounds__(320) void k_nms(const uint64_t* __restrict__ pmask,
                                             const uint32_t* __restrict__ misc,
                                             uint64_t* __restrict__ keepw) {
  __shared__ uint64_t tile[2][64 * 64];  // 2 x 32 KB
  __shared__ int s_stop[2];
  const int c = blockIdx.x;
  const int tid = threadIdx.x;
  const int wv = tid >> 6;
  const int ln = tid & 63;
  const uint64_t* pm = pmask + (size_t)c * NPRE * 64;

  if (tid == 0) { s_stop[0] = 0; s_stop[1] = 0; }
  if (wv > 0) {
    int l = tid - 64;
    const ulonglong2* src2 = (const ulonglong2*)pm;
    ulonglong2* dst2 = (ulonglong2*)tile[0];
#pragma unroll
    for (int q = 0; q < 8; ++q) dst2[q * 256 + l] = src2[q * 256 + l];
  }
  __syncthreads();

  uint64_t avail = 0, keepbits = 0;
  int cnt = 0;
  if (wv == 0) {
    uint32_t Vth = misc[12 + c];       // valid prefix length in sorted space
    uint32_t lo = (uint32_t)(ln * 64);
    avail = (Vth >= lo + 64) ? ~0ull
          : ((Vth <= lo) ? 0ull : ((1ull << (Vth - lo)) - 1ull));
  }

  for (int T = 0; T < 64; ++T) {
    const int cb = T & 1;
    if (wv > 0) {
      if (T + 1 < 64) {
        int l = tid - 64;
        const ulonglong2* src2 = (const ulonglong2*)(pm + (size_t)(T + 1) * 64 * 64);
        ulonglong2* dst2 = (ulonglong2*)tile[cb ^ 1];
#pragma unroll
        for (int q = 0; q < 8; ++q) dst2[q * 256 + l] = src2[q * 256 + l];
      }
    } else {
      const uint64_t* tp = tile[cb];
      uint64_t awT = readlane64(avail, T);
      uint64_t pf[8];
#pragma unroll
      for (int u = 0; u < 8; ++u) pf[u] = tp[u * 64 + ln];
      uint64_t kwT = 0;
#pragma unroll
      for (int r = 0; r < 64; ++r) {
        uint64_t cur = pf[r & 7];
        if (r + 8 < 64) pf[r & 7] = tp[(r + 8) * 64 + ln];
        bool kp = ((awT >> r) & 1ull) != 0ull;
        if (kp) {
          avail &= ~cur;
          awT &= ~readlane64(cur, T);
          kwT |= (1ull << r);
        }
      }
      if (ln == T) keepbits = kwT;
      cnt += (int)__popcll(kwT);
      if (ln == 0 && cnt >= MAXNUM) s_stop[cb] = 1;
    }
    __syncthreads();
    if (s_stop[cb]) break;
  }
  if (wv == 0) keepw[c * 64 + ln] = keepbits;
}

// 8) per-class stable-compact first <=500 kept keys into outk[2048] (padded).
__global__ __launch_bounds__(1024) void k_collect(const uint64_t* __restrict__ keepw,
                                                  const uint32_t* __restrict__ ord,
                                                  const float* __restrict__ sc3,
                                                  uint64_t* __restrict__ outk,
                                                  uint32_t* __restrict__ misc) {
  const int c = blockIdx.x, t = threadIdx.x, w = t >> 6, ln = t & 63;
  if (c == 3) {  // tail pad
    int i = 3 * MAXNUM + t;
    if (i < 2048) outk[i] = PADKEY;
    return;
  }
  __shared__ uint32_t wsum[16];
  uint32_t bits4 = 0;
#pragma unroll
  for (int q = 0; q < 4; ++q) {
    int i = t * 4 + q;
    uint32_t b = (uint32_t)((keepw[c * 64 + (i >> 6)] >> (i & 63)) & 1ull);
    bits4 |= b << q;
  }
  uint32_t cnt = __popc(bits4);
  uint32_t incl = cnt;
#pragma unroll
  for (int d = 1; d < 64; d <<= 1) { uint32_t u = __shfl_up(incl, d, 64); if (ln >= d) incl += u; }
  if (ln == 63) wsum[w] = incl;
  __syncthreads();
  uint32_t wb = 0, total = 0;
#pragma unroll
  for (int i = 0; i < 16; ++i) { uint32_t v = wsum[i]; total += v; if (i < w) wb += v; }
  uint32_t r = wb + incl - cnt;  // exclusive prefix
#pragma unroll
  for (int q = 0; q < 4; ++q) {
    if ((bits4 >> q) & 1u) {
      if (r < (uint32_t)MAXNUM) {
        uint32_t pos = ord[c * NPRE + t * 4 + q];
        uint32_t sb = __float_as_uint(sc3[pos * 3 + c]);
        outk[c * MAXNUM + r] = (((uint64_t)(~sb)) << 32) | (uint32_t)(c * NPRE + pos);
      }
      ++r;
    }
  }
  uint32_t Vc = total < (uint32_t)MAXNUM ? total : (uint32_t)MAXNUM;
  if (t == 0) misc[8 + c] = Vc;
  for (uint32_t s = Vc + t; s < (uint32_t)MAXNUM; s += 1024)
    outk[c * MAXNUM + s] = PADKEY;
}

// 9) rank the full 2048-key union (32 blocks x 4 waves x 16 rows = 2048);
//    emit rank<500; zero-fill [V,500).
__global__ __launch_bounds__(256) void k_emit(const uint64_t* __restrict__ outk,
                                              const uint32_t* __restrict__ misc,
                                              const float* __restrict__ bb7,
                                              const uint32_t* __restrict__ dsc,
                                              float* __restrict__ out) {
  const int tid = threadIdx.x, ln = tid & 63;
  const int wave = blockIdx.x * 4 + (tid >> 6);  // 0..127
  const int base = wave * 16;                    // rows 0..2047
  uint64_t kr[16];
#pragma unroll
  for (int r = 0; r < 16; ++r) kr[r] = outk[base + r];
  uint32_t rnk[16];
#pragma unroll
  for (int r = 0; r < 16; ++r) rnk[r] = 0;
  for (int ch = 0; ch < 2048 / 64; ++ch) {
    uint64_t ck = outk[ch * 64 + ln];
#pragma unroll
    for (int r = 0; r < 16; ++r)
      rnk[r] += (uint32_t)__popcll(__ballot(ck < kr[r]));
  }
  if (ln == 0) {
#pragma unroll
    for (int r = 0; r < 16; ++r) {
      uint64_t key = kr[r];
      uint32_t rk = rnk[r];
      if (key != PADKEY && rk < (uint32_t)MAXNUM) {
        uint32_t flat = (uint32_t)key;
        float score = __uint_as_float(~((uint32_t)(key >> 32)));
        int cc = (int)(flat >> 12);
        int pos = (int)(flat & 4095u);
        const float* b = bb7 + (size_t)pos * 7;
        float rr0 = b[6];
        float dir_rot = rr0 + HPIF - floorf(rr0 + 0.5f) * PIF;
        float rr = dir_rot - HPIF + PIF * (float)dsc[pos];
#pragma unroll
        for (int q = 0; q < 6; ++q) out[rk * 7 + q] = b[q];
        out[rk * 7 + 6] = rr;
        out[7 * MAXNUM + rk] = score;
        out[8 * MAXNUM + rk] = (float)cc;
      }
    }
  }
  if (blockIdx.x == 0) {
    uint32_t V = misc[8] + misc[9] + misc[10];
    for (uint32_t s = V + tid; s < (uint32_t)MAXNUM; s += 256) {
#pragma unroll
      for (int q = 0; q < 7; ++q) out[s * 7 + q] = 0.0f;
      out[7 * MAXNUM + s] = 0.0f;
      out[8 * MAXNUM + s] = -1.0f;
    }
  }
}

// ---------------- launcher ----------------
extern "C" void kernel_launch(void* const* d_in, const int* in_sizes, int n_in,
                              void* d_out, int out_size, void* d_ws, size_t ws_size,
                              hipStream_t stream) {
  (void)in_sizes; (void)n_in; (void)out_size; (void)ws_size;
  const float* cls    = (const float*)d_in[0];
  const float* bbp    = (const float*)d_in[1];
  const float* dirp   = (const float*)d_in[2];
  const float* priors = (const float*)d_in[3];
  char* ws = (char*)d_ws;

  uint32_t* hist   = (uint32_t*)(ws + HIST_OFF);
  uint32_t* misc   = (uint32_t*)(ws + MISC_OFF);
  float*    ms     = (float*)(ws + MS_OFF);
  uint64_t* cand   = (uint64_t*)(ws + CAND_OFF);
  uint32_t* sel    = (uint32_t*)(ws + SEL_OFF);
  float*    sc3    = (float*)(ws + SC3_OFF);
  uint32_t* dsc    = (uint32_t*)(ws + DSC_OFF);
  float*    bb7    = (float*)(ws + BB7_OFF);
  float*    box4   = (float*)(ws + BOX4_OFF);
  float*    areaA  = (float*)(ws + AREA_OFF);
  uint32_t* ord    = (uint32_t*)(ws + ORD_OFF);
  uint64_t* pmask  = (uint64_t*)(ws + PMASK_OFF);
  uint64_t* keepw  = (uint64_t*)(ws + KEEPW_OFF);
  uint64_t* outk   = (uint64_t*)(ws + OUTK_OFF);

  hipMemsetAsync(ws, 0, ZERO_BYTES, stream);  // hist + misc in one call
  k_score<<<NB_H, 256, 0, stream>>>(cls, ms, hist);
  k_compact<<<(NANCH + 4095) / 4096, 256, 0, stream>>>(hist, ms, misc, cand);
  k_rank<<<CAND_CAP / (4 * 16), 256, 0, stream>>>(cand, misc, sel);
  k_gather<<<NPRE / 256, 256, 0, stream>>>(sel, cls, bbp, dirp, priors, sc3, dsc, bb7, box4, areaA, misc);
  k_rankcls<<<dim3(NPRE / (4 * 16), 3), 256, 0, stream>>>(sc3, ord);
  k_mask<<<dim3(64, 64, 3), 64, 0, stream>>>(ord, box4, areaA, pmask);
  k_nms<<<3, 320, 0, stream>>>(pmask, misc, keepw);
  k_collect<<<4, 1024, 0, stream>>>(keepw, ord, sc3, outk, misc);
  k_emit<<<2048 / (4 * 16), 256, 0, stream>>>(outk, misc, bb7, dsc, (float*)d_out);
}